// Round 1
// baseline (982.005 us; speedup 1.0000x reference)
//
#include <hip/hip_runtime.h>
#include <hip/hip_bf16.h>
#include <math.h>

#define MUL_S 64
#define MUL_V 32
#define FEAT  160          // 64 + 3*32
#define VN    2000
#define NN    200000

// scale constants
__device__ __forceinline__ float silu_n(float x) {
    return x * (1.0f / (1.0f + __expf(-x))) * 1.679059f;
}

#define INV8       0.125f
#define INV_SQRT32 0.17677669529663687f
#define INV_SQRT3  0.57735026918962576f
#define INV_SQRT96 0.10206207261596575f
#define INV_S3S96  0.05892556509887896f   /* 1/(sqrt(3)*sqrt(96)) */
#define INV_SQRT2  0.70710678118654752f
#define INV_SQRT_AVG 0.1f

// ---------------------------------------------------------------------------
// Phase 1: per node n:
//   sn = o3_linear(x_node, Ws_nsc, Wv_nsc)          -> out_node (temp storage)
//   m  = fc_tp(x_node, sh, WA, WB, WC, WD)          -> atomicAdd into m_acc[batch[n]]
// 32 nodes / block, 8 threads / node (thread computes 8 s-chan + 4 v-chan).
// ---------------------------------------------------------------------------
__global__ __launch_bounds__(256) void phase1(
    const float* __restrict__ x_node,
    const float* __restrict__ sh,
    const float* __restrict__ Ws_nsc, const float* __restrict__ Wv_nsc,
    const float* __restrict__ WA, const float* __restrict__ WB,
    const float* __restrict__ WC, const float* __restrict__ WD,
    const int*   __restrict__ batch,
    float* __restrict__ out_node,    // [NN][FEAT] : holds sn after phase1
    float* __restrict__ m_acc)       // [VN][FEAT] : zeroed before launch
{
    __shared__ float xs[32][FEAT + 1];   // +1 pad: stride 161 -> conflict-free
    __shared__ float shs[32][4];

    const int block0 = blockIdx.x * 32;

    for (int idx = threadIdx.x; idx < 32 * FEAT; idx += 256) {
        int r = idx / FEAT, c = idx - r * FEAT;
        xs[r][c] = x_node[(size_t)(block0 + r) * FEAT + c];
    }
    for (int idx = threadIdx.x; idx < 32 * 4; idx += 256) {
        int r = idx >> 2, c = idx & 3;
        shs[r][c] = sh[(size_t)(block0 + r) * 4 + c];
    }
    __syncthreads();

    const int r = threadIdx.x >> 3;   // node within block
    const int g = threadIdx.x & 7;    // feature group
    const int n = block0 + r;

    const float sh0  = shs[r][0];
    const float sh1a = shs[r][1], sh1b = shs[r][2], sh1c = shs[r][3];

    float acc_sn[8] = {0.f,0.f,0.f,0.f,0.f,0.f,0.f,0.f};
    float acc_ms[8] = {0.f,0.f,0.f,0.f,0.f,0.f,0.f,0.f};
    float acc_wd[4] = {0.f,0.f,0.f,0.f};

    // ---- scalar-channel K loop (k = 0..63) ----
    for (int k = 0; k < MUL_S; ++k) {
        float xv = xs[r][k];
        float xh = xv * sh0;
        const float* wsrow = Ws_nsc + k * MUL_S;
        const float* warow = WA     + k * MUL_S;
        const float* wdrow = WD     + k * MUL_V;
#pragma unroll
        for (int jj = 0; jj < 8; ++jj) {
            int j = g + 8 * jj;
            acc_sn[jj] = fmaf(xv, wsrow[j], acc_sn[jj]);
            acc_ms[jj] = fmaf(xh, warow[j], acc_ms[jj]);
        }
#pragma unroll
        for (int ww = 0; ww < 4; ++ww) {
            int w = g + 8 * ww;
            acc_wd[ww] = fmaf(xv, wdrow[w], acc_wd[ww]);
        }
    }

    // ---- vector-channel U loop (u = 0..31) ----
    float acc_snv[4][3] = {};
    float acc_mvc[4][3] = {};
    for (int u = 0; u < MUL_V; ++u) {
        float v0 = xs[r][MUL_S + 3 * u + 0];
        float v1 = xs[r][MUL_S + 3 * u + 1];
        float v2 = xs[r][MUL_S + 3 * u + 2];
        float dotu = (v0 * sh1a + v1 * sh1b + v2 * sh1c) * INV_SQRT3;
        const float* wbrow = WB     + u * MUL_S;
        const float* wvrow = Wv_nsc + u * MUL_V;
        const float* wcrow = WC     + u * MUL_V;
#pragma unroll
        for (int jj = 0; jj < 8; ++jj) {
            int j = g + 8 * jj;
            acc_ms[jj] = fmaf(dotu, wbrow[j], acc_ms[jj]);
        }
#pragma unroll
        for (int ww = 0; ww < 4; ++ww) {
            int w = g + 8 * ww;
            float wv = wvrow[w];
            float wc = wcrow[w];
            acc_snv[ww][0] = fmaf(v0, wv, acc_snv[ww][0]);
            acc_snv[ww][1] = fmaf(v1, wv, acc_snv[ww][1]);
            acc_snv[ww][2] = fmaf(v2, wv, acc_snv[ww][2]);
            acc_mvc[ww][0] = fmaf(v0, wc, acc_mvc[ww][0]);
            acc_mvc[ww][1] = fmaf(v1, wc, acc_mvc[ww][1]);
            acc_mvc[ww][2] = fmaf(v2, wc, acc_mvc[ww][2]);
        }
    }

    // ---- write sn (temp) ----
    float* outrow = out_node + (size_t)n * FEAT;
#pragma unroll
    for (int jj = 0; jj < 8; ++jj)
        outrow[g + 8 * jj] = acc_sn[jj] * INV8;
#pragma unroll
    for (int ww = 0; ww < 4; ++ww) {
        int w = g + 8 * ww;
        outrow[MUL_S + 3 * w + 0] = acc_snv[ww][0] * INV_SQRT32;
        outrow[MUL_S + 3 * w + 1] = acc_snv[ww][1] * INV_SQRT32;
        outrow[MUL_S + 3 * w + 2] = acc_snv[ww][2] * INV_SQRT32;
    }

    // ---- accumulate message into m_acc[batch[n]] ----
    const int b = batch[n];
    float* mrow = m_acc + (size_t)b * FEAT;
#pragma unroll
    for (int jj = 0; jj < 8; ++jj)
        atomicAdd(&mrow[g + 8 * jj], acc_ms[jj] * INV_SQRT96);
#pragma unroll
    for (int ww = 0; ww < 4; ++ww) {
        int w = g + 8 * ww;
        atomicAdd(&mrow[MUL_S + 3 * w + 0], (acc_mvc[ww][0] * sh0 + acc_wd[ww] * sh1a) * INV_S3S96);
        atomicAdd(&mrow[MUL_S + 3 * w + 1], (acc_mvc[ww][1] * sh0 + acc_wd[ww] * sh1b) * INV_S3S96);
        atomicAdd(&mrow[MUL_S + 3 * w + 2], (acc_mvc[ww][2] * sh0 + acc_wd[ww] * sh1c) * INV_S3S96);
    }
}

// ---------------------------------------------------------------------------
// Phase 2: per virtual node b:
//   sv = o3_linear(x_virtual, Ws_vsc, Wv_vsc)
//   m  = act(m_acc * 0.1)
//   out_virtual = (sv + m) / sqrt(2)
// ---------------------------------------------------------------------------
__global__ __launch_bounds__(256) void phase2(
    const float* __restrict__ x_virtual,
    const float* __restrict__ Ws_vsc, const float* __restrict__ Wv_vsc,
    const float* __restrict__ m_acc,
    float* __restrict__ out_virtual)
{
    __shared__ float xs[32][FEAT + 1];

    const int block0 = blockIdx.x * 32;

    for (int idx = threadIdx.x; idx < 32 * FEAT; idx += 256) {
        int r = idx / FEAT, c = idx - r * FEAT;
        int n = block0 + r;
        xs[r][c] = (n < VN) ? x_virtual[(size_t)n * FEAT + c] : 0.f;
    }
    __syncthreads();

    const int r = threadIdx.x >> 3;
    const int g = threadIdx.x & 7;
    const int n = block0 + r;
    if (n >= VN) return;

    float acc_s[8] = {0.f,0.f,0.f,0.f,0.f,0.f,0.f,0.f};
    for (int k = 0; k < MUL_S; ++k) {
        float xv = xs[r][k];
        const float* wrow = Ws_vsc + k * MUL_S;
#pragma unroll
        for (int jj = 0; jj < 8; ++jj)
            acc_s[jj] = fmaf(xv, wrow[g + 8 * jj], acc_s[jj]);
    }
    float acc_v[4][3] = {};
    for (int u = 0; u < MUL_V; ++u) {
        float v0 = xs[r][MUL_S + 3 * u + 0];
        float v1 = xs[r][MUL_S + 3 * u + 1];
        float v2 = xs[r][MUL_S + 3 * u + 2];
        const float* wrow = Wv_vsc + u * MUL_V;
#pragma unroll
        for (int ww = 0; ww < 4; ++ww) {
            float wv = wrow[g + 8 * ww];
            acc_v[ww][0] = fmaf(v0, wv, acc_v[ww][0]);
            acc_v[ww][1] = fmaf(v1, wv, acc_v[ww][1]);
            acc_v[ww][2] = fmaf(v2, wv, acc_v[ww][2]);
        }
    }

    const float* mrow = m_acc + (size_t)n * FEAT;
    float* outrow = out_virtual + (size_t)n * FEAT;
#pragma unroll
    for (int jj = 0; jj < 8; ++jj) {
        int j = g + 8 * jj;
        float sv = acc_s[jj] * INV8;
        float ms = silu_n(mrow[j] * INV_SQRT_AVG);
        outrow[j] = (sv + ms) * INV_SQRT2;
    }
#pragma unroll
    for (int ww = 0; ww < 4; ++ww) {
        int w = g + 8 * ww;
#pragma unroll
        for (int i = 0; i < 3; ++i) {
            float sv = acc_v[ww][i] * INV_SQRT32;
            float mv = mrow[MUL_S + 3 * w + i] * INV_SQRT_AVG;
            outrow[MUL_S + 3 * w + i] = (sv + mv) * INV_SQRT2;
        }
    }
}

// ---------------------------------------------------------------------------
// Phase 3: per node n:
//   g  = out_virtual[batch[n]]
//   gn = act(o3_linear(g, Ws_n2v, Wv_n2v))
//   out_node = (sn + gn) / sqrt(2)        (sn read in-place from out_node)
// ---------------------------------------------------------------------------
__global__ __launch_bounds__(256) void phase3(
    const float* __restrict__ out_virtual,
    const int*   __restrict__ batch,
    const float* __restrict__ Ws_n2v, const float* __restrict__ Wv_n2v,
    float* __restrict__ out_node)
{
    __shared__ float xs[32][FEAT + 1];
    __shared__ int   bs[32];

    const int block0 = blockIdx.x * 32;

    if (threadIdx.x < 32) bs[threadIdx.x] = batch[block0 + threadIdx.x];
    __syncthreads();
    for (int idx = threadIdx.x; idx < 32 * FEAT; idx += 256) {
        int r = idx / FEAT, c = idx - r * FEAT;
        xs[r][c] = out_virtual[(size_t)bs[r] * FEAT + c];
    }
    __syncthreads();

    const int r = threadIdx.x >> 3;
    const int g = threadIdx.x & 7;
    const int n = block0 + r;

    float acc_s[8] = {0.f,0.f,0.f,0.f,0.f,0.f,0.f,0.f};
    for (int k = 0; k < MUL_S; ++k) {
        float xv = xs[r][k];
        const float* wrow = Ws_n2v + k * MUL_S;
#pragma unroll
        for (int jj = 0; jj < 8; ++jj)
            acc_s[jj] = fmaf(xv, wrow[g + 8 * jj], acc_s[jj]);
    }
    float acc_v[4][3] = {};
    for (int u = 0; u < MUL_V; ++u) {
        float v0 = xs[r][MUL_S + 3 * u + 0];
        float v1 = xs[r][MUL_S + 3 * u + 1];
        float v2 = xs[r][MUL_S + 3 * u + 2];
        const float* wrow = Wv_n2v + u * MUL_V;
#pragma unroll
        for (int ww = 0; ww < 4; ++ww) {
            float wv = wrow[g + 8 * ww];
            acc_v[ww][0] = fmaf(v0, wv, acc_v[ww][0]);
            acc_v[ww][1] = fmaf(v1, wv, acc_v[ww][1]);
            acc_v[ww][2] = fmaf(v2, wv, acc_v[ww][2]);
        }
    }

    float* outrow = out_node + (size_t)n * FEAT;
#pragma unroll
    for (int jj = 0; jj < 8; ++jj) {
        int j = g + 8 * jj;
        float gs = silu_n(acc_s[jj] * INV8);
        outrow[j] = (outrow[j] + gs) * INV_SQRT2;
    }
#pragma unroll
    for (int ww = 0; ww < 4; ++ww) {
        int w = g + 8 * ww;
#pragma unroll
        for (int i = 0; i < 3; ++i) {
            float gv = acc_v[ww][i] * INV_SQRT32;
            int c = MUL_S + 3 * w + i;
            outrow[c] = (outrow[c] + gv) * INV_SQRT2;
        }
    }
}

// ---------------------------------------------------------------------------
extern "C" void kernel_launch(void* const* d_in, const int* in_sizes, int n_in,
                              void* d_out, int out_size, void* d_ws, size_t ws_size,
                              hipStream_t stream)
{
    const float* x_virtual = (const float*)d_in[0];
    const float* x_node    = (const float*)d_in[1];
    const float* sh        = (const float*)d_in[2];
    const float* Ws_vsc    = (const float*)d_in[3];
    const float* Wv_vsc    = (const float*)d_in[4];
    const float* Ws_nsc    = (const float*)d_in[5];
    const float* Wv_nsc    = (const float*)d_in[6];
    const float* WA        = (const float*)d_in[7];
    const float* WB        = (const float*)d_in[8];
    const float* WC        = (const float*)d_in[9];
    const float* WD        = (const float*)d_in[10];
    const float* Ws_n2v    = (const float*)d_in[11];
    const float* Wv_n2v    = (const float*)d_in[12];
    const int*   batch     = (const int*)d_in[13];

    float* out         = (float*)d_out;
    float* out_virtual = out;                 // [VN][FEAT]
    float* out_node    = out + VN * FEAT;     // [NN][FEAT]
    float* m_acc       = (float*)d_ws;        // [VN][FEAT]

    hipMemsetAsync(m_acc, 0, (size_t)VN * FEAT * sizeof(float), stream);

    phase1<<<NN / 32, 256, 0, stream>>>(x_node, sh, Ws_nsc, Wv_nsc,
                                        WA, WB, WC, WD, batch, out_node, m_acc);
    phase2<<<(VN + 31) / 32, 256, 0, stream>>>(x_virtual, Ws_vsc, Wv_vsc,
                                               m_acc, out_virtual);
    phase3<<<NN / 32, 256, 0, stream>>>(out_virtual, batch, Ws_n2v, Wv_n2v,
                                        out_node);
}

// Round 2
// 298.367 us; speedup vs baseline: 3.2913x; 3.2913x over previous
//
#include <hip/hip_runtime.h>
#include <hip/hip_bf16.h>
#include <math.h>

#define MUL_S 64
#define MUL_V 32
#define FEAT  160          // 64 + 3*32
#define PAD   4
#define VN    2000
#define NN    200000

__device__ __forceinline__ float silu_n(float x) {
    return x * (1.0f / (1.0f + __expf(-x))) * 1.679059f;
}

#define INV8         0.125f
#define INV_SQRT32   0.17677669529663687f
#define INV_SQRT3    0.57735026918962576f
#define INV_SQRT96   0.10206207261596575f
#define INV_S3S96    0.05892556509887896f   /* 1/(sqrt(3)*sqrt(96)) */
#define INV_SQRT2    0.70710678118654752f
#define INV_SQRT_AVG 0.1f

// copy n floats (n%4==0) global->LDS as float4, 256 threads
#define COPYW(dst, src, n)                                                  \
    for (int _i = threadIdx.x; _i < (n) / 4; _i += 256)                     \
        ((float4*)(dst))[_i] = ((const float4*)(src))[_i];

// ---------------------------------------------------------------------------
// Phase 1: per node n:
//   sn = o3_linear(x_node, Ws_nsc, Wv_nsc)  -> out_node (temp storage)
//   m  = fc_tp(x_node, sh, ...)             -> block-segmented-sum -> atomicAdd
// 32 nodes/block, 8 threads/node. Thread (r,g) owns scalar cols [8g,8g+8)
// and vector channels [4g,4g+4). Weights staged in LDS (57 KB).
// ---------------------------------------------------------------------------
__global__ __launch_bounds__(256) void phase1(
    const float* __restrict__ x_node,
    const float* __restrict__ sh,
    const float* __restrict__ Ws_nsc, const float* __restrict__ Wv_nsc,
    const float* __restrict__ WA, const float* __restrict__ WB,
    const float* __restrict__ WC, const float* __restrict__ WD,
    const int*   __restrict__ batch,
    float* __restrict__ out_node,    // [NN][FEAT]
    float* __restrict__ m_acc)       // [VN][FEAT], zeroed
{
    __shared__ float xs[32][FEAT + PAD];       // x rows; reused for m reduce
    __shared__ float w_s[MUL_S * MUL_S];
    __shared__ float w_a[MUL_S * MUL_S];
    __shared__ float w_d[MUL_S * MUL_V];
    __shared__ float w_b[MUL_V * MUL_S];
    __shared__ float w_v[MUL_V * MUL_V];
    __shared__ float w_c[MUL_V * MUL_V];
    __shared__ float shs[32][4];
    __shared__ int   bs[32];

    const int block0 = blockIdx.x * 32;

    if (threadIdx.x < 32) bs[threadIdx.x] = batch[block0 + threadIdx.x];
    for (int idx = threadIdx.x; idx < 32 * 4; idx += 256)
        shs[idx >> 2][idx & 3] = sh[(size_t)block0 * 4 + idx];
    // x rows: 32*160 floats = 1280 float4
    for (int i4 = threadIdx.x; i4 < 32 * (FEAT / 4); i4 += 256) {
        int r = i4 / (FEAT / 4), c4 = i4 - r * (FEAT / 4);
        *(float4*)&xs[r][c4 * 4] =
            ((const float4*)(x_node + (size_t)(block0 + r) * FEAT))[c4];
    }
    COPYW(w_s, Ws_nsc, MUL_S * MUL_S)
    COPYW(w_a, WA,     MUL_S * MUL_S)
    COPYW(w_d, WD,     MUL_S * MUL_V)
    COPYW(w_b, WB,     MUL_V * MUL_S)
    COPYW(w_v, Wv_nsc, MUL_V * MUL_V)
    COPYW(w_c, WC,     MUL_V * MUL_V)
    __syncthreads();

    const int r = threadIdx.x >> 3;
    const int g = threadIdx.x & 7;
    const int n = block0 + r;

    const float sh0 = shs[r][0];
    const float sh1v[3] = { shs[r][1], shs[r][2], shs[r][3] };

    float acc_sn[8] = {};
    float acc_ms[8] = {};
    float acc_wd[4] = {};
    float acc_snv[4][3] = {};
    float acc_mvc[4][3] = {};

    // ---- scalar-channel K loop ----
    for (int k4 = 0; k4 < MUL_S; k4 += 4) {
        const float4 xq = *(const float4*)&xs[r][k4];
#pragma unroll
        for (int e = 0; e < 4; ++e) {
            const int k = k4 + e;
            const float xv = (&xq.x)[e];
            const float xh = xv * sh0;
            float wsv[8], wav[8], wdv[4];
            *(float4*)&wsv[0] = *(const float4*)&w_s[k * MUL_S + g * 8];
            *(float4*)&wsv[4] = *(const float4*)&w_s[k * MUL_S + g * 8 + 4];
            *(float4*)&wav[0] = *(const float4*)&w_a[k * MUL_S + g * 8];
            *(float4*)&wav[4] = *(const float4*)&w_a[k * MUL_S + g * 8 + 4];
            *(float4*)&wdv[0] = *(const float4*)&w_d[k * MUL_V + g * 4];
#pragma unroll
            for (int jj = 0; jj < 8; ++jj) {
                acc_sn[jj] = fmaf(xv, wsv[jj], acc_sn[jj]);
                acc_ms[jj] = fmaf(xh, wav[jj], acc_ms[jj]);
            }
#pragma unroll
            for (int ww = 0; ww < 4; ++ww)
                acc_wd[ww] = fmaf(xv, wdv[ww], acc_wd[ww]);
        }
    }

    // ---- vector-channel U loop ----
    for (int u = 0; u < MUL_V; ++u) {
        const float v0 = xs[r][MUL_S + 3 * u + 0];
        const float v1 = xs[r][MUL_S + 3 * u + 1];
        const float v2 = xs[r][MUL_S + 3 * u + 2];
        const float dotu =
            (v0 * sh1v[0] + v1 * sh1v[1] + v2 * sh1v[2]) * INV_SQRT3;
        float wbv[8], wvv[4], wcv[4];
        *(float4*)&wbv[0] = *(const float4*)&w_b[u * MUL_S + g * 8];
        *(float4*)&wbv[4] = *(const float4*)&w_b[u * MUL_S + g * 8 + 4];
        *(float4*)&wvv[0] = *(const float4*)&w_v[u * MUL_V + g * 4];
        *(float4*)&wcv[0] = *(const float4*)&w_c[u * MUL_V + g * 4];
#pragma unroll
        for (int jj = 0; jj < 8; ++jj)
            acc_ms[jj] = fmaf(dotu, wbv[jj], acc_ms[jj]);
#pragma unroll
        for (int ww = 0; ww < 4; ++ww) {
            acc_snv[ww][0] = fmaf(v0, wvv[ww], acc_snv[ww][0]);
            acc_snv[ww][1] = fmaf(v1, wvv[ww], acc_snv[ww][1]);
            acc_snv[ww][2] = fmaf(v2, wvv[ww], acc_snv[ww][2]);
            acc_mvc[ww][0] = fmaf(v0, wcv[ww], acc_mvc[ww][0]);
            acc_mvc[ww][1] = fmaf(v1, wcv[ww], acc_mvc[ww][1]);
            acc_mvc[ww][2] = fmaf(v2, wcv[ww], acc_mvc[ww][2]);
        }
    }

    // ---- write sn (temp) as float4 ----
    {
        float* outrow = out_node + (size_t)n * FEAT;
        float t[8];
#pragma unroll
        for (int jj = 0; jj < 8; ++jj) t[jj] = acc_sn[jj] * INV8;
        *(float4*)&outrow[g * 8]     = *(float4*)&t[0];
        *(float4*)&outrow[g * 8 + 4] = *(float4*)&t[4];
        float tv[12];
#pragma unroll
        for (int ww = 0; ww < 4; ++ww)
#pragma unroll
            for (int i = 0; i < 3; ++i)
                tv[ww * 3 + i] = acc_snv[ww][i] * INV_SQRT32;
        *(float4*)&outrow[MUL_S + g * 12]     = *(float4*)&tv[0];
        *(float4*)&outrow[MUL_S + g * 12 + 4] = *(float4*)&tv[4];
        *(float4*)&outrow[MUL_S + g * 12 + 8] = *(float4*)&tv[8];
    }

    // ---- m into LDS (reuse xs), then block-segmented sum + atomics ----
    __syncthreads();   // all xs reads done
#pragma unroll
    for (int jj = 0; jj < 8; ++jj)
        xs[r][g * 8 + jj] = acc_ms[jj] * INV_SQRT96;
#pragma unroll
    for (int ww = 0; ww < 4; ++ww)
#pragma unroll
        for (int i = 0; i < 3; ++i)
            xs[r][MUL_S + g * 12 + ww * 3 + i] =
                (acc_mvc[ww][i] * sh0 + acc_wd[ww] * sh1v[i]) * INV_S3S96;
    __syncthreads();

    const int c = threadIdx.x;
    if (c < FEAT) {
        float run = xs[0][c];
        int bprev = bs[0];
#pragma unroll 4
        for (int rr = 1; rr < 32; ++rr) {
            int b = bs[rr];             // uniform across wave -> no divergence
            if (b != bprev) {
                atomicAdd(&m_acc[(size_t)bprev * FEAT + c], run);
                run = 0.f;
                bprev = b;
            }
            run += xs[rr][c];
        }
        atomicAdd(&m_acc[(size_t)bprev * FEAT + c], run);
    }
}

// ---------------------------------------------------------------------------
// Phase 2: per virtual node b (tiny: 2000 rows)
// ---------------------------------------------------------------------------
__global__ __launch_bounds__(256) void phase2(
    const float* __restrict__ x_virtual,
    const float* __restrict__ Ws_vsc, const float* __restrict__ Wv_vsc,
    const float* __restrict__ m_acc,
    float* __restrict__ out_virtual)
{
    __shared__ float xs[32][FEAT + PAD];

    const int block0 = blockIdx.x * 32;

    for (int idx = threadIdx.x; idx < 32 * FEAT; idx += 256) {
        int r = idx / FEAT, c = idx - r * FEAT;
        int n = block0 + r;
        xs[r][c] = (n < VN) ? x_virtual[(size_t)n * FEAT + c] : 0.f;
    }
    __syncthreads();

    const int r = threadIdx.x >> 3;
    const int g = threadIdx.x & 7;
    const int n = block0 + r;
    if (n >= VN) return;

    float acc_s[8] = {};
    for (int k = 0; k < MUL_S; ++k) {
        float xv = xs[r][k];
        const float* wrow = Ws_vsc + k * MUL_S + g * 8;
#pragma unroll
        for (int jj = 0; jj < 8; ++jj)
            acc_s[jj] = fmaf(xv, wrow[jj], acc_s[jj]);
    }
    float acc_v[4][3] = {};
    for (int u = 0; u < MUL_V; ++u) {
        float v0 = xs[r][MUL_S + 3 * u + 0];
        float v1 = xs[r][MUL_S + 3 * u + 1];
        float v2 = xs[r][MUL_S + 3 * u + 2];
        const float* wrow = Wv_vsc + u * MUL_V + g * 4;
#pragma unroll
        for (int ww = 0; ww < 4; ++ww) {
            float wv = wrow[ww];
            acc_v[ww][0] = fmaf(v0, wv, acc_v[ww][0]);
            acc_v[ww][1] = fmaf(v1, wv, acc_v[ww][1]);
            acc_v[ww][2] = fmaf(v2, wv, acc_v[ww][2]);
        }
    }

    const float* mrow = m_acc + (size_t)n * FEAT;
    float* outrow = out_virtual + (size_t)n * FEAT;
#pragma unroll
    for (int jj = 0; jj < 8; ++jj) {
        int j = g * 8 + jj;
        float sv = acc_s[jj] * INV8;
        float ms = silu_n(mrow[j] * INV_SQRT_AVG);
        outrow[j] = (sv + ms) * INV_SQRT2;
    }
#pragma unroll
    for (int ww = 0; ww < 4; ++ww) {
#pragma unroll
        for (int i = 0; i < 3; ++i) {
            int cc = MUL_S + (g * 4 + ww) * 3 + i;
            float sv = acc_v[ww][i] * INV_SQRT32;
            float mv = mrow[cc] * INV_SQRT_AVG;
            outrow[cc] = (sv + mv) * INV_SQRT2;
        }
    }
}

// ---------------------------------------------------------------------------
// Phase 3: per node n:
//   g  = out_virtual[batch[n]];  gn = act(o3_linear(g, Ws_n2v, Wv_n2v))
//   out_node = (sn + gn) / sqrt(2)   (sn read in place, float4 RMW)
// ---------------------------------------------------------------------------
__global__ __launch_bounds__(256) void phase3(
    const float* __restrict__ out_virtual,
    const int*   __restrict__ batch,
    const float* __restrict__ Ws_n2v, const float* __restrict__ Wv_n2v,
    float* __restrict__ out_node)
{
    __shared__ float xs[32][FEAT + PAD];
    __shared__ float w_s[MUL_S * MUL_S];
    __shared__ float w_v[MUL_V * MUL_V];
    __shared__ int   bs[32];

    const int block0 = blockIdx.x * 32;

    if (threadIdx.x < 32) bs[threadIdx.x] = batch[block0 + threadIdx.x];
    COPYW(w_s, Ws_n2v, MUL_S * MUL_S)
    COPYW(w_v, Wv_n2v, MUL_V * MUL_V)
    __syncthreads();
    for (int i4 = threadIdx.x; i4 < 32 * (FEAT / 4); i4 += 256) {
        int r = i4 / (FEAT / 4), c4 = i4 - r * (FEAT / 4);
        *(float4*)&xs[r][c4 * 4] =
            ((const float4*)(out_virtual + (size_t)bs[r] * FEAT))[c4];
    }
    __syncthreads();

    const int r = threadIdx.x >> 3;
    const int g = threadIdx.x & 7;
    const int n = block0 + r;

    float acc_s[8] = {};
    for (int k4 = 0; k4 < MUL_S; k4 += 4) {
        const float4 xq = *(const float4*)&xs[r][k4];
#pragma unroll
        for (int e = 0; e < 4; ++e) {
            const int k = k4 + e;
            const float xv = (&xq.x)[e];
            float wsv[8];
            *(float4*)&wsv[0] = *(const float4*)&w_s[k * MUL_S + g * 8];
            *(float4*)&wsv[4] = *(const float4*)&w_s[k * MUL_S + g * 8 + 4];
#pragma unroll
            for (int jj = 0; jj < 8; ++jj)
                acc_s[jj] = fmaf(xv, wsv[jj], acc_s[jj]);
        }
    }
    float acc_v[4][3] = {};
    for (int u = 0; u < MUL_V; ++u) {
        const float v0 = xs[r][MUL_S + 3 * u + 0];
        const float v1 = xs[r][MUL_S + 3 * u + 1];
        const float v2 = xs[r][MUL_S + 3 * u + 2];
        float wvv[4];
        *(float4*)&wvv[0] = *(const float4*)&w_v[u * MUL_V + g * 4];
#pragma unroll
        for (int ww = 0; ww < 4; ++ww) {
            acc_v[ww][0] = fmaf(v0, wvv[ww], acc_v[ww][0]);
            acc_v[ww][1] = fmaf(v1, wvv[ww], acc_v[ww][1]);
            acc_v[ww][2] = fmaf(v2, wvv[ww], acc_v[ww][2]);
        }
    }

    float* outrow = out_node + (size_t)n * FEAT;
    {
        float4 o0 = *(float4*)&outrow[g * 8];
        float4 o1 = *(float4*)&outrow[g * 8 + 4];
        float t[8];
#pragma unroll
        for (int jj = 0; jj < 8; ++jj) t[jj] = silu_n(acc_s[jj] * INV8);
        o0.x = (o0.x + t[0]) * INV_SQRT2; o0.y = (o0.y + t[1]) * INV_SQRT2;
        o0.z = (o0.z + t[2]) * INV_SQRT2; o0.w = (o0.w + t[3]) * INV_SQRT2;
        o1.x = (o1.x + t[4]) * INV_SQRT2; o1.y = (o1.y + t[5]) * INV_SQRT2;
        o1.z = (o1.z + t[6]) * INV_SQRT2; o1.w = (o1.w + t[7]) * INV_SQRT2;
        *(float4*)&outrow[g * 8]     = o0;
        *(float4*)&outrow[g * 8 + 4] = o1;
    }
    {
        float tv[12];
#pragma unroll
        for (int ww = 0; ww < 4; ++ww)
#pragma unroll
            for (int i = 0; i < 3; ++i)
                tv[ww * 3 + i] = acc_v[ww][i] * INV_SQRT32;
#pragma unroll
        for (int q = 0; q < 3; ++q) {
            float4 o = *(float4*)&outrow[MUL_S + g * 12 + q * 4];
            o.x = (o.x + tv[q * 4 + 0]) * INV_SQRT2;
            o.y = (o.y + tv[q * 4 + 1]) * INV_SQRT2;
            o.z = (o.z + tv[q * 4 + 2]) * INV_SQRT2;
            o.w = (o.w + tv[q * 4 + 3]) * INV_SQRT2;
            *(float4*)&outrow[MUL_S + g * 12 + q * 4] = o;
        }
    }
}

// ---------------------------------------------------------------------------
extern "C" void kernel_launch(void* const* d_in, const int* in_sizes, int n_in,
                              void* d_out, int out_size, void* d_ws, size_t ws_size,
                              hipStream_t stream)
{
    const float* x_virtual = (const float*)d_in[0];
    const float* x_node    = (const float*)d_in[1];
    const float* sh        = (const float*)d_in[2];
    const float* Ws_vsc    = (const float*)d_in[3];
    const float* Wv_vsc    = (const float*)d_in[4];
    const float* Ws_nsc    = (const float*)d_in[5];
    const float* Wv_nsc    = (const float*)d_in[6];
    const float* WA        = (const float*)d_in[7];
    const float* WB        = (const float*)d_in[8];
    const float* WC        = (const float*)d_in[9];
    const float* WD        = (const float*)d_in[10];
    const float* Ws_n2v    = (const float*)d_in[11];
    const float* Wv_n2v    = (const float*)d_in[12];
    const int*   batch     = (const int*)d_in[13];

    float* out         = (float*)d_out;
    float* out_virtual = out;                 // [VN][FEAT]
    float* out_node    = out + VN * FEAT;     // [NN][FEAT]
    float* m_acc       = (float*)d_ws;        // [VN][FEAT]

    hipMemsetAsync(m_acc, 0, (size_t)VN * FEAT * sizeof(float), stream);

    phase1<<<NN / 32, 256, 0, stream>>>(x_node, sh, Ws_nsc, Wv_nsc,
                                        WA, WB, WC, WD, batch, out_node, m_acc);
    phase2<<<(VN + 31) / 32, 256, 0, stream>>>(x_virtual, Ws_vsc, Wv_vsc,
                                               m_acc, out_virtual);
    phase3<<<NN / 32, 256, 0, stream>>>(out_virtual, batch, Ws_n2v, Wv_n2v,
                                        out_node);
}